// Round 11
// baseline (2151.111 us; speedup 1.0000x reference)
//
#include <hip/hip_runtime.h>
#include <math.h>

#define T_STEPS 2048
#define HID     128
#define G4      512   // 4*H
#define CH      8     // pipeline chunk (timesteps)  [R15: 16->8, halves fill]
#define NCHUNK  (T_STEPS / CH)   // 256

typedef _Float16 half8 __attribute__((ext_vector_type(8)));
typedef float    f32x4 __attribute__((ext_vector_type(4)));

__device__ __forceinline__ float fast_sig(float x) {
    return __fdividef(1.0f, 1.0f + __expf(-x));
}
__device__ __forceinline__ float fast_tanh(float x) {
    return fmaf(2.0f, __fdividef(1.0f, 1.0f + __expf(-2.0f * x)), -1.0f);
}

// ---------------------------------------------------------------------------
// ROUND 15 == ROUND 14 + residual micro-levers (pre-committed decision round).
//
// R14 confirmed the G-latency theory: 2110->1873 us, pipe at 906 ns/step --
// at/below the best measured single-layer pace (R9: 930). Per-step time has
// been invariant across 8 structural configs; remaining model gap attributed
// to single-wave MFMA issue rate + exposed LDS/act chain (not attackable
// without reducing the forced 128 MFMA/step of this GEMV shape).
//
// Changes vs R14 (nothing else):
//   1. CH 16->8: B2 start delay ~18 -> ~9.5 us. flags1/flags2 = 256 entries
//      (memset 2048 B covers both). B1 stages 8 rows (tid<128), G-store
//      guarded col<8; h1s rows 8..15 zeroed once (unused MFMA cols benign).
//   2. k-split accumulator chains in B0/B2: accL chains kt0,kt1; accH chains
//      kt2,kt3; scalar add at select. Chain depth 4->2.
//
// Structure (unchanged):
//   B0 (L0):  R9 recurrence; h1 (f16) to global; releases flags1[c]/chunk.
//   B1 (G):   per chunk: acquire flags1[c], stage h1 chunk to LDS,
//             G = Wih1 @ h1c, store G, release flags2[c].
//   B2 (L1):  R9 L1 + bsum4 bias + depth-2 G prefetch + chunk gate at t+2.
// ---------------------------------------------------------------------------
__global__ __launch_bounds__(256)
void lstm_pipe3(const float* __restrict__ Whh0,   // (512,128)
                const float* __restrict__ Whh1,   // (512,128)
                const float* __restrict__ Wih1,   // (512,128)
                const float* __restrict__ x,      // (2048,128)
                const float* __restrict__ wih0,   // (512,)
                const float* __restrict__ bih0,
                const float* __restrict__ bhh0,
                const float* __restrict__ bih1,
                const float* __restrict__ bhh1,
                unsigned int* __restrict__ flags1, // (256,) zeroed per launch
                unsigned int* __restrict__ flags2, // (256,) zeroed per launch
                _Float16* __restrict__ h1h,        // (2048,128) f16
                float* __restrict__ G,             // (2048,512) f32
                float* __restrict__ hout2)         // (2048,128) f32
{
    const int tid  = threadIdx.x;
    const int wave = tid >> 6;         // 0..3
    const int lane = tid & 63;
    const int quad = lane >> 4;
    const int col  = lane & 15;
    const int bid  = blockIdx.x;       // 0=L0, 1=G-GEMM, 2=L1

    const bool act_lane = (col < 8);
    const int  hh = (col >> 2) & 1;
    const int  rr = col & 3;
    const int  u  = wave * 32 + hh * 16 + quad * 4 + rr;   // hidden unit

    __shared__ __align__(16) _Float16 h16[2][HID];     // broadcast h (dbuf)
    __shared__ __align__(16) _Float16 h1s[16][136];    // B1: staged h1 chunk
    __shared__ float x_s[T_STEPS];                     // B0: x[t,127] table
    __shared__ char occupancy_pad[70400];              // total = 83456 B ->
                                                       // 1 WG/CU, 512-reg RA
    ((volatile char*)occupancy_pad)[tid] = 0;

    const f32x4 zero4 = {0.f, 0.f, 0.f, 0.f};

    if (bid == 1) {
        // ================= B1: G-GEMM worker =================
        // wfrag[mt][kt]: A-row = (wave*8+mt)*16 + col, k = kt*32 + quad*8
        half8 wfrag[8][4];
        #pragma unroll
        for (int mt = 0; mt < 8; ++mt) {
            const float* row = Wih1 + (size_t)((wave * 8 + mt) * 16 + col) * HID;
            #pragma unroll
            for (int kt = 0; kt < 4; ++kt) {
                const float4* p = reinterpret_cast<const float4*>(row + kt * 32 + quad * 8);
                float4 lo = p[0], hi = p[1];
                half8 h;
                h[0] = (_Float16)lo.x; h[1] = (_Float16)lo.y;
                h[2] = (_Float16)lo.z; h[3] = (_Float16)lo.w;
                h[4] = (_Float16)hi.x; h[5] = (_Float16)hi.y;
                h[6] = (_Float16)hi.z; h[7] = (_Float16)hi.w;
                wfrag[mt][kt] = h;
            }
        }
        #pragma unroll
        for (int mt = 0; mt < 8; ++mt)
            #pragma unroll
            for (int kt = 0; kt < 4; ++kt) asm volatile("" : "+a"(wfrag[mt][kt]));

        // zero h1s once (rows 8..15 feed unused MFMA columns; keep them finite)
        for (int i = tid; i < 16 * 136; i += 256)
            (&h1s[0][0])[i] = (_Float16)0.0f;
        __syncthreads();

        for (int c = 0; c < NCHUNK; ++c) {
            if (lane == 0) {
                while (__hip_atomic_load(&flags1[c],
                           __ATOMIC_ACQUIRE, __HIP_MEMORY_SCOPE_AGENT) == 0u)
                    __builtin_amdgcn_s_sleep(1);
            }
            // stage h1 chunk: 128 threads x half8 = 8 rows x 128 f16
            if (tid < 128) {
                const int row = tid >> 4, c16 = tid & 15;
                half8 v = *reinterpret_cast<const half8*>(
                    h1h + (size_t)(c * CH + row) * HID + c16 * 8);
                *reinterpret_cast<half8*>(&h1s[row][c16 * 8]) = v;
            }
            __syncthreads();
            // G chunk: wave covers gates [wave*128, wave*128+128)
            #pragma unroll
            for (int mt = 0; mt < 8; ++mt) {
                f32x4 ag = zero4;
                #pragma unroll
                for (int kt = 0; kt < 4; ++kt) {
                    half8 bg = *reinterpret_cast<const half8*>(
                        &h1s[col][kt * 32 + quad * 8]);
                    ag = __builtin_amdgcn_mfma_f32_16x16x32_f16(wfrag[mt][kt], bg, ag, 0, 0, 0);
                }
                // D[m = gate within wave, n = col (timestep)]; cols>=CH invalid
                if (col < CH)
                    *reinterpret_cast<float4*>(
                        &G[(size_t)(c * CH + col) * G4 + (wave * 8 + mt) * 16 + quad * 4]) =
                        make_float4(ag[0], ag[1], ag[2], ag[3]);
            }
            __syncthreads();   // drains all threads' G stores (vmcnt(0))
            if (tid == 0)
                __hip_atomic_store(&flags2[c], 1u,
                                   __ATOMIC_RELEASE, __HIP_MEMORY_SCOPE_AGENT);
        }
        return;
    }

    // ================= B0 / B2: recurrences (R9 structure) =================
    const bool isL0 = (bid == 0);
    const float* Whh = isL0 ? Whh0 : Whh1;
    half8 afrag[8][4];
    #pragma unroll
    for (int r = 0; r < 8; ++r) {
        const float* row = Whh +
            (size_t)(128 * (r >> 1) + wave * 32 + (r & 1) * 16 + col) * HID;
        #pragma unroll
        for (int kt = 0; kt < 4; ++kt) {
            const float4* p = reinterpret_cast<const float4*>(row + kt * 32 + quad * 8);
            float4 lo = p[0], hi = p[1];
            half8 h;
            h[0] = (_Float16)lo.x; h[1] = (_Float16)lo.y;
            h[2] = (_Float16)lo.z; h[3] = (_Float16)lo.w;
            h[4] = (_Float16)hi.x; h[5] = (_Float16)hi.y;
            h[6] = (_Float16)hi.z; h[7] = (_Float16)hi.w;
            afrag[r][kt] = h;
        }
    }
    #pragma unroll
    for (int r = 0; r < 8; ++r)
        #pragma unroll
        for (int kt = 0; kt < 4; ++kt) asm volatile("" : "+a"(afrag[r][kt]));

    f32x4 bsum4 = {0,0,0,0}, w4 = {0,0,0,0};
    if (act_lane) {
        #pragma unroll
        for (int g = 0; g < 4; ++g) {
            if (isL0) {
                bsum4[g] = bih0[128 * g + u] + bhh0[128 * g + u];
                w4[g]    = wih0[128 * g + u];
            } else {
                bsum4[g] = bih1[128 * g + u] + bhh1[128 * g + u];
            }
        }
    }
    asm volatile("" : "+v"(bsum4), "+v"(w4));

    if (isL0) {
        for (int i = tid; i < T_STEPS; i += 256)
            x_s[i] = x[(size_t)i * HID + HID - 1];
    }

    if (tid < HID) h16[0][tid] = (_Float16)0.0f;
    __syncthreads();

    float c_reg = 0.0f;

    if (isL0) {
        // ---------------- B0: layer-0 ----------------
        for (int t = 0; t < T_STEPS; ++t) {
            half8 b0 = *reinterpret_cast<const half8*>(&h16[t & 1][ 0 + quad * 8]);
            half8 b1 = *reinterpret_cast<const half8*>(&h16[t & 1][32 + quad * 8]);
            half8 b2 = *reinterpret_cast<const half8*>(&h16[t & 1][64 + quad * 8]);
            half8 b3 = *reinterpret_cast<const half8*>(&h16[t & 1][96 + quad * 8]);

            // k-split chains: accL = k0,k1 ; accH = k2,k3 (depth 2 each)
            f32x4 accL[8], accH[8];
            #pragma unroll
            for (int r = 0; r < 8; ++r)
                accL[r] = __builtin_amdgcn_mfma_f32_16x16x32_f16(afrag[r][0], b0, zero4, 0, 0, 0);
            #pragma unroll
            for (int r = 0; r < 8; ++r)
                accH[r] = __builtin_amdgcn_mfma_f32_16x16x32_f16(afrag[r][2], b2, zero4, 0, 0, 0);
            #pragma unroll
            for (int r = 0; r < 8; ++r)
                accL[r] = __builtin_amdgcn_mfma_f32_16x16x32_f16(afrag[r][1], b1, accL[r], 0, 0, 0);
            #pragma unroll
            for (int r = 0; r < 8; ++r)
                accH[r] = __builtin_amdgcn_mfma_f32_16x16x32_f16(afrag[r][3], b3, accH[r], 0, 0, 0);

            float gi = 0.f, gf = 0.f, gg = 0.f, go = 0.f;
            #pragma unroll
            for (int cs = 0; cs < 8; ++cs) {
                if (col == cs) {
                    const int h2_ = cs >> 2, r2_ = cs & 3;
                    gi = accL[0 + h2_][r2_] + accH[0 + h2_][r2_];
                    gf = accL[2 + h2_][r2_] + accH[2 + h2_][r2_];
                    gg = accL[4 + h2_][r2_] + accH[4 + h2_][r2_];
                    go = accL[6 + h2_][r2_] + accH[6 + h2_][r2_];
                }
            }
            f32x4 pre = bsum4 + w4 * x_s[t];
            gi += pre[0]; gf += pre[1]; gg += pre[2]; go += pre[3];

            const float ai = fast_sig(gi);
            const float af = fast_sig(gf);
            const float ag = fast_tanh(gg);
            const float ao = fast_sig(go);
            c_reg = fmaf(af, c_reg, ai * ag);
            const float h = ao * fast_tanh(c_reg);

            if (act_lane) {
                const _Float16 hf = (_Float16)h;
                h16[(t + 1) & 1][u] = hf;
                h1h[(size_t)t * HID + u] = hf;
            }
            __syncthreads();   // vmcnt(0) drain -> h1h stores in L2

            if ((t & (CH - 1)) == (CH - 1) && tid == 0)
                __hip_atomic_store(&flags1[t >> 3], 1u,
                                   __ATOMIC_RELEASE, __HIP_MEMORY_SCOPE_AGENT);
        }
    } else {
        // ---------------- B2: layer-1 (depth-2 G prefetch) ----------------
        // prologue: wait for G chunk 0, preload pre for steps 0 and 1
        if (lane == 0) {
            while (__hip_atomic_load(&flags2[0],
                       __ATOMIC_ACQUIRE, __HIP_MEMORY_SCOPE_AGENT) == 0u)
                __builtin_amdgcn_s_sleep(1);
        }
        f32x4 pre_cur = {0,0,0,0}, pre_nxt = {0,0,0,0}, pre_fut = {0,0,0,0};
        if (act_lane) {
            #pragma unroll
            for (int g = 0; g < 4; ++g) {
                pre_cur[g] = G[128 * g + u];              // G[0]
                pre_nxt[g] = G[(size_t)G4 + 128 * g + u]; // G[1]
            }
        }

        for (int t = 0; t < T_STEPS; ++t) {
            // gate for the chunk containing t+2 (the prefetch target)
            const int tp = t + 2;
            if (tp < T_STEPS && (tp & (CH - 1)) == 0) {
                const int cn = tp >> 3;
                if (lane == 0) {
                    while (__hip_atomic_load(&flags2[cn],
                               __ATOMIC_ACQUIRE, __HIP_MEMORY_SCOPE_AGENT) == 0u)
                        __builtin_amdgcn_s_sleep(1);
                }
            }
            const int tf = (tp < T_STEPS) ? tp : T_STEPS - 1;

            half8 b0 = *reinterpret_cast<const half8*>(&h16[t & 1][ 0 + quad * 8]);
            half8 b1 = *reinterpret_cast<const half8*>(&h16[t & 1][32 + quad * 8]);
            half8 b2 = *reinterpret_cast<const half8*>(&h16[t & 1][64 + quad * 8]);
            half8 b3 = *reinterpret_cast<const half8*>(&h16[t & 1][96 + quad * 8]);

            // depth-2 prefetch: issue G[t+2] now; consumed two barriers later
            if (act_lane) {
                #pragma unroll
                for (int g = 0; g < 4; ++g)
                    pre_fut[g] = G[(size_t)tf * G4 + 128 * g + u];
            }
            asm volatile("" : "+v"(pre_fut));

            // k-split chains (depth 2 each)
            f32x4 accL[8], accH[8];
            #pragma unroll
            for (int r = 0; r < 8; ++r)
                accL[r] = __builtin_amdgcn_mfma_f32_16x16x32_f16(afrag[r][0], b0, zero4, 0, 0, 0);
            #pragma unroll
            for (int r = 0; r < 8; ++r)
                accH[r] = __builtin_amdgcn_mfma_f32_16x16x32_f16(afrag[r][2], b2, zero4, 0, 0, 0);
            #pragma unroll
            for (int r = 0; r < 8; ++r)
                accL[r] = __builtin_amdgcn_mfma_f32_16x16x32_f16(afrag[r][1], b1, accL[r], 0, 0, 0);
            #pragma unroll
            for (int r = 0; r < 8; ++r)
                accH[r] = __builtin_amdgcn_mfma_f32_16x16x32_f16(afrag[r][3], b3, accH[r], 0, 0, 0);

            float gi = 0.f, gf = 0.f, gg = 0.f, go = 0.f;
            #pragma unroll
            for (int cs = 0; cs < 8; ++cs) {
                if (col == cs) {
                    const int h2_ = cs >> 2, r2_ = cs & 3;
                    gi = accL[0 + h2_][r2_] + accH[0 + h2_][r2_];
                    gf = accL[2 + h2_][r2_] + accH[2 + h2_][r2_];
                    gg = accL[4 + h2_][r2_] + accH[4 + h2_][r2_];
                    go = accL[6 + h2_][r2_] + accH[6 + h2_][r2_];
                }
            }
            // raw G has no bias (B1 computes Wih1@h1 only)
            gi += pre_cur[0] + bsum4[0];
            gf += pre_cur[1] + bsum4[1];
            gg += pre_cur[2] + bsum4[2];
            go += pre_cur[3] + bsum4[3];

            const float ai = fast_sig(gi);
            const float af = fast_sig(gf);
            const float ag = fast_tanh(gg);
            const float ao = fast_sig(go);
            c_reg = fmaf(af, c_reg, ai * ag);
            const float h = ao * fast_tanh(c_reg);

            if (act_lane) {
                h16[(t + 1) & 1][u] = (_Float16)h;
                hout2[(size_t)t * HID + u] = h;
            }
            pre_cur = pre_nxt;
            pre_nxt = pre_fut;
            __syncthreads();
        }
    }
}

// ---------------------------------------------------------------------------
// C[m,n] = sum_k A[m,k] * W[n,k] + b1[n] (+ b2[n])    K = 128 fixed
// ---------------------------------------------------------------------------
#define BM 64
#define BN 64
__global__ __launch_bounds__(256)
void gemm_bias_kernel(const float* __restrict__ A,   // (M,128)
                      const float* __restrict__ W,   // (N,128)
                      const float* __restrict__ b1,
                      const float* __restrict__ b2,  // may be null
                      float* __restrict__ C,         // (M,N)
                      int M, int N)
{
    __shared__ float Al[128][BM + 4];
    __shared__ float Wl[128][BN + 4];
    const int tid    = threadIdx.x;
    const int m_base = blockIdx.x * BM;
    const int n_base = blockIdx.y * BN;

    {
        const int r  = tid >> 2;          // 0..63
        const int kq = (tid & 3) * 32;    // 0,32,64,96
        const float4* srcA = reinterpret_cast<const float4*>(A + (size_t)(m_base + r) * 128 + kq);
        #pragma unroll
        for (int i = 0; i < 8; ++i) {
            float4 v = srcA[i];
            int k = kq + 4 * i;
            Al[k + 0][r] = v.x; Al[k + 1][r] = v.y; Al[k + 2][r] = v.z; Al[k + 3][r] = v.w;
        }
        const float4* srcW = reinterpret_cast<const float4*>(W + (size_t)(n_base + r) * 128 + kq);
        #pragma unroll
        for (int i = 0; i < 8; ++i) {
            float4 v = srcW[i];
            int k = kq + 4 * i;
            Wl[k + 0][r] = v.x; Wl[k + 1][r] = v.y; Wl[k + 2][r] = v.z; Wl[k + 3][r] = v.w;
        }
    }
    __syncthreads();

    const int tm = (tid & 15) * 4;
    const int tn = (tid >> 4) * 4;
    float acc[4][4] = {};
    #pragma unroll 8
    for (int k = 0; k < 128; ++k) {
        float4 av = *reinterpret_cast<const float4*>(&Al[k][tm]);
        float4 wv = *reinterpret_cast<const float4*>(&Wl[k][tn]);
        acc[0][0] = fmaf(av.x, wv.x, acc[0][0]);
        acc[0][1] = fmaf(av.x, wv.y, acc[0][1]);
        acc[0][2] = fmaf(av.x, wv.z, acc[0][2]);
        acc[0][3] = fmaf(av.x, wv.w, acc[0][3]);
        acc[1][0] = fmaf(av.y, wv.x, acc[1][0]);
        acc[1][1] = fmaf(av.y, wv.y, acc[1][1]);
        acc[1][2] = fmaf(av.y, wv.z, acc[1][2]);
        acc[1][3] = fmaf(av.y, wv.w, acc[1][3]);
        acc[2][0] = fmaf(av.z, wv.x, acc[2][0]);
        acc[2][1] = fmaf(av.z, wv.y, acc[2][1]);
        acc[2][2] = fmaf(av.z, wv.z, acc[2][2]);
        acc[2][3] = fmaf(av.z, wv.w, acc[2][3]);
        acc[3][0] = fmaf(av.w, wv.x, acc[3][0]);
        acc[3][1] = fmaf(av.w, wv.y, acc[3][1]);
        acc[3][2] = fmaf(av.w, wv.z, acc[3][2]);
        acc[3][3] = fmaf(av.w, wv.w, acc[3][3]);
    }

    float bias[4];
    #pragma unroll
    for (int i = 0; i < 4; ++i) {
        int n = n_base + tn + i;
        bias[i] = b1[n] + (b2 ? b2[n] : 0.0f);
    }
    #pragma unroll
    for (int mi = 0; mi < 4; ++mi) {
        float4 o;
        o.x = acc[mi][0] + bias[0];
        o.y = acc[mi][1] + bias[1];
        o.z = acc[mi][2] + bias[2];
        o.w = acc[mi][3] + bias[3];
        *reinterpret_cast<float4*>(C + (size_t)(m_base + tm + mi) * N + n_base + tn) = o;
    }
}

// ---------------------------------------------------------------------------
__global__ __launch_bounds__(512)
void bn_stats_kernel(const float* __restrict__ Z,       // (T,128)
                     const float* __restrict__ gamma,
                     const float* __restrict__ beta,
                     float* __restrict__ scale,
                     float* __restrict__ shift)
{
    const int tid = threadIdx.x;
    const int col = tid & 127;
    const int seg = tid >> 7;     // 0..3
    float s = 0.f, sq = 0.f;
    for (int t = seg * 512; t < (seg + 1) * 512; ++t) {
        float v = Z[(size_t)t * 128 + col];
        s += v;
        sq = fmaf(v, v, sq);
    }
    __shared__ float ps[4][128], pq[4][128];
    ps[seg][col] = s;
    pq[seg][col] = sq;
    __syncthreads();
    if (tid < 128) {
        float sum = ps[0][tid] + ps[1][tid] + ps[2][tid] + ps[3][tid];
        float sqq = pq[0][tid] + pq[1][tid] + pq[2][tid] + pq[3][tid];
        float mean = sum * (1.0f / 2048.0f);
        float var  = sqq * (1.0f / 2048.0f) - mean * mean;
        float sc = gamma[tid] * rsqrtf(var + 1e-5f);
        scale[tid] = sc;
        shift[tid] = beta[tid] - mean * sc;
    }
}

// ---------------------------------------------------------------------------
__global__ __launch_bounds__(512)
void fc2_kernel(const float* __restrict__ Z,      // (T,128)
                const float* __restrict__ scale,
                const float* __restrict__ shift,
                const float* __restrict__ fc2_w,  // (8,128)
                const float* __restrict__ fc2_b,
                float* __restrict__ out)          // (T,8)
{
    const int gid = blockIdx.x * blockDim.x + threadIdx.x;   // 0..16383
    const int o = gid & 7;
    const int t = gid >> 3;

    __shared__ float w_s[8][132];
    __shared__ float sc_s[128], sh_s[128];
    for (int i = threadIdx.x; i < 1024; i += 512) w_s[i >> 7][i & 127] = fc2_w[i];
    if (threadIdx.x < 128) {
        sc_s[threadIdx.x] = scale[threadIdx.x];
        sh_s[threadIdx.x] = shift[threadIdx.x];
    }
    __syncthreads();

    float acc = fc2_b[o];
    const float* zrow = Z + (size_t)t * 128;
    #pragma unroll 4
    for (int k = 0; k < 128; ++k) {
        float zn = fmaf(zrow[k], sc_s[k], sh_s[k]);
        zn = fmaxf(zn, 0.0f);
        acc = fmaf(zn, w_s[o][k], acc);
    }
    out[gid] = acc;
}

// ---------------------------------------------------------------------------
extern "C" void kernel_launch(void* const* d_in, const int* in_sizes, int n_in,
                              void* d_out, int out_size, void* d_ws, size_t ws_size,
                              hipStream_t stream)
{
    const float* x     = (const float*)d_in[0];   // (2048,128,1)
    const float* Wih0  = (const float*)d_in[1];   // (512,1)
    const float* Whh0  = (const float*)d_in[2];   // (512,128)
    const float* bih0  = (const float*)d_in[3];
    const float* bhh0  = (const float*)d_in[4];
    const float* Wih1  = (const float*)d_in[5];   // (512,128)
    const float* Whh1  = (const float*)d_in[6];   // (512,128)
    const float* bih1  = (const float*)d_in[7];
    const float* bhh1  = (const float*)d_in[8];
    const float* fc1_w = (const float*)d_in[9];   // (128,128)
    const float* fc1_b = (const float*)d_in[10];
    const float* gamma = (const float*)d_in[11];
    const float* beta  = (const float*)d_in[12];
    const float* fc2_w = (const float*)d_in[13];  // (8,128)
    const float* fc2_b = (const float*)d_in[14];
    float* out = (float*)d_out;                    // (2048,8) fp32

    unsigned int* flags1 = (unsigned int*)d_ws;                   // 256 u32
    unsigned int* flags2 = flags1 + 256;                          // 256 u32
    _Float16* h1h  = (_Float16*)((char*)d_ws + 2048);             // 2048*128 f16
    float*    G    = (float*)((char*)d_ws + 2048 + T_STEPS * HID * 2);  // 2048*512
    float*    h2   = G + (size_t)T_STEPS * G4;
    float*    z    = h2 + T_STEPS * HID;
    float*    scale= z  + T_STEPS * HID;
    float*    shift= scale + 128;

    // reset chunk flags each launch (graph-capturable stream op)
    hipMemsetAsync(flags1, 0, 2048, stream);

    // K1: 3-CU pipeline (B0 = L0, B1 = G-GEMM, B2 = L1)
    lstm_pipe3<<<3, 256, 0, stream>>>(Whh0, Whh1, Wih1, x, Wih0,
                                      bih0, bhh0, bih1, bhh1,
                                      flags1, flags2, h1h, G, h2);

    // K4a: z = h2 @ fc1^T + fc1_b
    dim3 g4(T_STEPS / BM, HID / BN);
    gemm_bias_kernel<<<g4, 256, 0, stream>>>(h2, fc1_w, fc1_b, nullptr, z, T_STEPS, HID);

    // K4b: batchnorm stats over T axis
    bn_stats_kernel<<<1, 512, 0, stream>>>(z, gamma, beta, scale, shift);

    // K4c: normalize + relu + fc2
    fc2_kernel<<<T_STEPS * 8 / 512, 512, 0, stream>>>(z, scale, shift, fc2_w, fc2_b, out);
}

// Round 12
// 1870.990 us; speedup vs baseline: 1.1497x; 1.1497x over previous
//
#include <hip/hip_runtime.h>
#include <math.h>

#define T_STEPS 2048
#define HID     128
#define G4      512   // 4*H
#define CH      16    // pipeline chunk (timesteps)  [R16: reverted to R14]
#define NCHUNK  (T_STEPS / CH)

typedef _Float16 half8 __attribute__((ext_vector_type(8)));
typedef float    f32x4 __attribute__((ext_vector_type(4)));

__device__ __forceinline__ float fast_sig(float x) {
    return __fdividef(1.0f, 1.0f + __expf(-x));
}
__device__ __forceinline__ float fast_tanh(float x) {
    return fmaf(2.0f, __fdividef(1.0f, 1.0f + __expf(-2.0f * x)), -1.0f);
}

// ---------------------------------------------------------------------------
// ROUND 16 == ROUND 14 exact revert (best verified: 1873 us, pipe 906 ns/step).
//
// R15 (CH=8 + k-split) regressed to 2151 us with clean fingerprints:
// bank conflicts doubled 8192->16384 (B1's chunk count doubled -> its LDS
// read volume and wasted-column MFMA work doubled), VALUBusy 0.256->0.328
// (doubled B1 loop + sync frequency), and per-chunk pipeline slack halved
// 15->7.4 us so flag-propagation latency intruded into B2's schedule.
//
// R14 structure (the keeper):
//   B0 (L0):  R9 recurrence; h1 (f16) to global; releases flags1[c] per
//             16-step chunk (RELEASE/AGENT after the barrier's vmcnt drain).
//   B1 (G):   per chunk: acquire flags1[c], stage h1 chunk to LDS,
//             G = Wih1 @ h1c (32 MFMA/wave, full 16-col), store G,
//             __syncthreads, release flags2[c].
//   B2 (L1):  R9 L1 + bsum4 bias + DEPTH-2 G prefetch (issue G[t+2] at
//             step t -> full step to cover HBM latency) + chunk gate at t+2.
//
// Ledger: per-step ~906-930 ns invariant across 9 structural configs
// (4/8 waves, +/-stores, +/-spill, 1/2 barriers, dbuf, prefetch depth 1/2,
// 1/2/3-CU partition, CH 8/16, k-split). Spill, store-drain, wave-count,
// barrier-count, G-latency all eliminated with counter-verified A/Bs.
// Remaining floor: 2048 forced-serial GEMV steps x ~900 ns (single-wave
// MFMA issue of 128 16x16x32 GEMVs + exposed LDS/act chain).
// ---------------------------------------------------------------------------
__global__ __launch_bounds__(256)
void lstm_pipe3(const float* __restrict__ Whh0,   // (512,128)
                const float* __restrict__ Whh1,   // (512,128)
                const float* __restrict__ Wih1,   // (512,128)
                const float* __restrict__ x,      // (2048,128)
                const float* __restrict__ wih0,   // (512,)
                const float* __restrict__ bih0,
                const float* __restrict__ bhh0,
                const float* __restrict__ bih1,
                const float* __restrict__ bhh1,
                unsigned int* __restrict__ flags1, // (128,) zeroed per launch
                unsigned int* __restrict__ flags2, // (128,) zeroed per launch
                _Float16* __restrict__ h1h,        // (2048,128) f16
                float* __restrict__ G,             // (2048,512) f32
                float* __restrict__ hout2)         // (2048,128) f32
{
    const int tid  = threadIdx.x;
    const int wave = tid >> 6;         // 0..3
    const int lane = tid & 63;
    const int quad = lane >> 4;
    const int col  = lane & 15;
    const int bid  = blockIdx.x;       // 0=L0, 1=G-GEMM, 2=L1

    const bool act_lane = (col < 8);
    const int  hh = (col >> 2) & 1;
    const int  rr = col & 3;
    const int  u  = wave * 32 + hh * 16 + quad * 4 + rr;   // hidden unit

    __shared__ __align__(16) _Float16 h16[2][HID];     // broadcast h (dbuf)
    __shared__ __align__(16) _Float16 h1s[CH][136];    // B1: staged h1 chunk
    __shared__ float x_s[T_STEPS];                     // B0: x[t,127] table
    __shared__ char occupancy_pad[70400];              // total = 83456 B ->
                                                       // 1 WG/CU, 512-reg RA
    ((volatile char*)occupancy_pad)[tid] = 0;

    const f32x4 zero4 = {0.f, 0.f, 0.f, 0.f};

    if (bid == 1) {
        // ================= B1: G-GEMM worker =================
        // wfrag[mt][kt]: A-row = (wave*8+mt)*16 + col, k = kt*32 + quad*8
        half8 wfrag[8][4];
        #pragma unroll
        for (int mt = 0; mt < 8; ++mt) {
            const float* row = Wih1 + (size_t)((wave * 8 + mt) * 16 + col) * HID;
            #pragma unroll
            for (int kt = 0; kt < 4; ++kt) {
                const float4* p = reinterpret_cast<const float4*>(row + kt * 32 + quad * 8);
                float4 lo = p[0], hi = p[1];
                half8 h;
                h[0] = (_Float16)lo.x; h[1] = (_Float16)lo.y;
                h[2] = (_Float16)lo.z; h[3] = (_Float16)lo.w;
                h[4] = (_Float16)hi.x; h[5] = (_Float16)hi.y;
                h[6] = (_Float16)hi.z; h[7] = (_Float16)hi.w;
                wfrag[mt][kt] = h;
            }
        }
        #pragma unroll
        for (int mt = 0; mt < 8; ++mt)
            #pragma unroll
            for (int kt = 0; kt < 4; ++kt) asm volatile("" : "+a"(wfrag[mt][kt]));

        for (int c = 0; c < NCHUNK; ++c) {
            if (lane == 0) {
                while (__hip_atomic_load(&flags1[c],
                           __ATOMIC_ACQUIRE, __HIP_MEMORY_SCOPE_AGENT) == 0u)
                    __builtin_amdgcn_s_sleep(1);
            }
            // stage h1 chunk: 256 threads x half8 = 16 rows x 128 f16
            {
                const int row = tid >> 4, c16 = tid & 15;
                half8 v = *reinterpret_cast<const half8*>(
                    h1h + (size_t)(c * CH + row) * HID + c16 * 8);
                *reinterpret_cast<half8*>(&h1s[row][c16 * 8]) = v;
            }
            __syncthreads();
            // G chunk: wave covers gates [wave*128, wave*128+128)
            #pragma unroll
            for (int mt = 0; mt < 8; ++mt) {
                f32x4 ag = zero4;
                #pragma unroll
                for (int kt = 0; kt < 4; ++kt) {
                    half8 bg = *reinterpret_cast<const half8*>(
                        &h1s[col][kt * 32 + quad * 8]);
                    ag = __builtin_amdgcn_mfma_f32_16x16x32_f16(wfrag[mt][kt], bg, ag, 0, 0, 0);
                }
                // D[m = mt*16+quad*4+reg (gate within wave), n = col (timestep)]
                *reinterpret_cast<float4*>(
                    &G[(size_t)(c * CH + col) * G4 + (wave * 8 + mt) * 16 + quad * 4]) =
                    make_float4(ag[0], ag[1], ag[2], ag[3]);
            }
            __syncthreads();   // drains all threads' G stores (vmcnt(0))
            if (tid == 0)
                __hip_atomic_store(&flags2[c], 1u,
                                   __ATOMIC_RELEASE, __HIP_MEMORY_SCOPE_AGENT);
        }
        return;
    }

    // ================= B0 / B2: recurrences (R9 structure) =================
    const bool isL0 = (bid == 0);
    const float* Whh = isL0 ? Whh0 : Whh1;
    half8 afrag[8][4];
    #pragma unroll
    for (int r = 0; r < 8; ++r) {
        const float* row = Whh +
            (size_t)(128 * (r >> 1) + wave * 32 + (r & 1) * 16 + col) * HID;
        #pragma unroll
        for (int kt = 0; kt < 4; ++kt) {
            const float4* p = reinterpret_cast<const float4*>(row + kt * 32 + quad * 8);
            float4 lo = p[0], hi = p[1];
            half8 h;
            h[0] = (_Float16)lo.x; h[1] = (_Float16)lo.y;
            h[2] = (_Float16)lo.z; h[3] = (_Float16)lo.w;
            h[4] = (_Float16)hi.x; h[5] = (_Float16)hi.y;
            h[6] = (_Float16)hi.z; h[7] = (_Float16)hi.w;
            afrag[r][kt] = h;
        }
    }
    #pragma unroll
    for (int r = 0; r < 8; ++r)
        #pragma unroll
        for (int kt = 0; kt < 4; ++kt) asm volatile("" : "+a"(afrag[r][kt]));

    f32x4 bsum4 = {0,0,0,0}, w4 = {0,0,0,0};
    if (act_lane) {
        #pragma unroll
        for (int g = 0; g < 4; ++g) {
            if (isL0) {
                bsum4[g] = bih0[128 * g + u] + bhh0[128 * g + u];
                w4[g]    = wih0[128 * g + u];
            } else {
                bsum4[g] = bih1[128 * g + u] + bhh1[128 * g + u];
            }
        }
    }
    asm volatile("" : "+v"(bsum4), "+v"(w4));

    if (isL0) {
        for (int i = tid; i < T_STEPS; i += 256)
            x_s[i] = x[(size_t)i * HID + HID - 1];
    }

    if (tid < HID) h16[0][tid] = (_Float16)0.0f;
    __syncthreads();

    float c_reg = 0.0f;

    if (isL0) {
        // ---------------- B0: layer-0 ----------------
        for (int t = 0; t < T_STEPS; ++t) {
            half8 b0 = *reinterpret_cast<const half8*>(&h16[t & 1][ 0 + quad * 8]);
            half8 b1 = *reinterpret_cast<const half8*>(&h16[t & 1][32 + quad * 8]);
            half8 b2 = *reinterpret_cast<const half8*>(&h16[t & 1][64 + quad * 8]);
            half8 b3 = *reinterpret_cast<const half8*>(&h16[t & 1][96 + quad * 8]);

            f32x4 acc[8];
            #pragma unroll
            for (int r = 0; r < 8; ++r)
                acc[r] = __builtin_amdgcn_mfma_f32_16x16x32_f16(afrag[r][0], b0, zero4, 0, 0, 0);
            #pragma unroll
            for (int r = 0; r < 8; ++r)
                acc[r] = __builtin_amdgcn_mfma_f32_16x16x32_f16(afrag[r][1], b1, acc[r], 0, 0, 0);
            #pragma unroll
            for (int r = 0; r < 8; ++r)
                acc[r] = __builtin_amdgcn_mfma_f32_16x16x32_f16(afrag[r][2], b2, acc[r], 0, 0, 0);
            #pragma unroll
            for (int r = 0; r < 8; ++r)
                acc[r] = __builtin_amdgcn_mfma_f32_16x16x32_f16(afrag[r][3], b3, acc[r], 0, 0, 0);

            float gi = 0.f, gf = 0.f, gg = 0.f, go = 0.f;
            #pragma unroll
            for (int cs = 0; cs < 8; ++cs) {
                if (col == cs) {
                    const int h2_ = cs >> 2, r2_ = cs & 3;
                    gi = acc[0 + h2_][r2_];
                    gf = acc[2 + h2_][r2_];
                    gg = acc[4 + h2_][r2_];
                    go = acc[6 + h2_][r2_];
                }
            }
            f32x4 pre = bsum4 + w4 * x_s[t];
            gi += pre[0]; gf += pre[1]; gg += pre[2]; go += pre[3];

            const float ai = fast_sig(gi);
            const float af = fast_sig(gf);
            const float ag = fast_tanh(gg);
            const float ao = fast_sig(go);
            c_reg = fmaf(af, c_reg, ai * ag);
            const float h = ao * fast_tanh(c_reg);

            if (act_lane) {
                const _Float16 hf = (_Float16)h;
                h16[(t + 1) & 1][u] = hf;
                h1h[(size_t)t * HID + u] = hf;
            }
            __syncthreads();   // vmcnt(0) drain -> h1h stores in L2

            if ((t & 15) == 15 && tid == 0)
                __hip_atomic_store(&flags1[t >> 4], 1u,
                                   __ATOMIC_RELEASE, __HIP_MEMORY_SCOPE_AGENT);
        }
    } else {
        // ---------------- B2: layer-1 (depth-2 G prefetch) ----------------
        // prologue: wait for G chunk 0, preload pre for steps 0 and 1
        if (lane == 0) {
            while (__hip_atomic_load(&flags2[0],
                       __ATOMIC_ACQUIRE, __HIP_MEMORY_SCOPE_AGENT) == 0u)
                __builtin_amdgcn_s_sleep(1);
        }
        f32x4 pre_cur = {0,0,0,0}, pre_nxt = {0,0,0,0}, pre_fut = {0,0,0,0};
        if (act_lane) {
            #pragma unroll
            for (int g = 0; g < 4; ++g) {
                pre_cur[g] = G[128 * g + u];             // G[0]
                pre_nxt[g] = G[(size_t)G4 + 128 * g + u]; // G[1]
            }
        }

        for (int t = 0; t < T_STEPS; ++t) {
            // gate for the chunk containing t+2 (the prefetch target)
            const int tp = t + 2;
            if (tp < T_STEPS && (tp & 15) == 0) {
                const int cn = tp >> 4;
                if (lane == 0) {
                    while (__hip_atomic_load(&flags2[cn],
                               __ATOMIC_ACQUIRE, __HIP_MEMORY_SCOPE_AGENT) == 0u)
                        __builtin_amdgcn_s_sleep(1);
                }
            }
            const int tf = (tp < T_STEPS) ? tp : T_STEPS - 1;

            half8 b0 = *reinterpret_cast<const half8*>(&h16[t & 1][ 0 + quad * 8]);
            half8 b1 = *reinterpret_cast<const half8*>(&h16[t & 1][32 + quad * 8]);
            half8 b2 = *reinterpret_cast<const half8*>(&h16[t & 1][64 + quad * 8]);
            half8 b3 = *reinterpret_cast<const half8*>(&h16[t & 1][96 + quad * 8]);

            // depth-2 prefetch: issue G[t+2] now; consumed two barriers later
            if (act_lane) {
                #pragma unroll
                for (int g = 0; g < 4; ++g)
                    pre_fut[g] = G[(size_t)tf * G4 + 128 * g + u];
            }
            asm volatile("" : "+v"(pre_fut));

            f32x4 acc[8];
            #pragma unroll
            for (int r = 0; r < 8; ++r)
                acc[r] = __builtin_amdgcn_mfma_f32_16x16x32_f16(afrag[r][0], b0, zero4, 0, 0, 0);
            #pragma unroll
            for (int r = 0; r < 8; ++r)
                acc[r] = __builtin_amdgcn_mfma_f32_16x16x32_f16(afrag[r][1], b1, acc[r], 0, 0, 0);
            #pragma unroll
            for (int r = 0; r < 8; ++r)
                acc[r] = __builtin_amdgcn_mfma_f32_16x16x32_f16(afrag[r][2], b2, acc[r], 0, 0, 0);
            #pragma unroll
            for (int r = 0; r < 8; ++r)
                acc[r] = __builtin_amdgcn_mfma_f32_16x16x32_f16(afrag[r][3], b3, acc[r], 0, 0, 0);

            float gi = 0.f, gf = 0.f, gg = 0.f, go = 0.f;
            #pragma unroll
            for (int cs = 0; cs < 8; ++cs) {
                if (col == cs) {
                    const int h2_ = cs >> 2, r2_ = cs & 3;
                    gi = acc[0 + h2_][r2_];
                    gf = acc[2 + h2_][r2_];
                    gg = acc[4 + h2_][r2_];
                    go = acc[6 + h2_][r2_];
                }
            }
            // raw G has no bias (B1 computes Wih1@h1 only)
            gi += pre_cur[0] + bsum4[0];
            gf += pre_cur[1] + bsum4[1];
            gg += pre_cur[2] + bsum4[2];
            go += pre_cur[3] + bsum4[3];

            const float ai = fast_sig(gi);
            const float af = fast_sig(gf);
            const float ag = fast_tanh(gg);
            const float ao = fast_sig(go);
            c_reg = fmaf(af, c_reg, ai * ag);
            const float h = ao * fast_tanh(c_reg);

            if (act_lane) {
                h16[(t + 1) & 1][u] = (_Float16)h;
                hout2[(size_t)t * HID + u] = h;
            }
            pre_cur = pre_nxt;
            pre_nxt = pre_fut;
            __syncthreads();
        }
    }
}

// ---------------------------------------------------------------------------
// C[m,n] = sum_k A[m,k] * W[n,k] + b1[n] (+ b2[n])    K = 128 fixed
// ---------------------------------------------------------------------------
#define BM 64
#define BN 64
__global__ __launch_bounds__(256)
void gemm_bias_kernel(const float* __restrict__ A,   // (M,128)
                      const float* __restrict__ W,   // (N,128)
                      const float* __restrict__ b1,
                      const float* __restrict__ b2,  // may be null
                      float* __restrict__ C,         // (M,N)
                      int M, int N)
{
    __shared__ float Al[128][BM + 4];
    __shared__ float Wl[128][BN + 4];
    const int tid    = threadIdx.x;
    const int m_base = blockIdx.x * BM;
    const int n_base = blockIdx.y * BN;

    {
        const int r  = tid >> 2;          // 0..63
        const int kq = (tid & 3) * 32;    // 0,32,64,96
        const float4* srcA = reinterpret_cast<const float4*>(A + (size_t)(m_base + r) * 128 + kq);
        #pragma unroll
        for (int i = 0; i < 8; ++i) {
            float4 v = srcA[i];
            int k = kq + 4 * i;
            Al[k + 0][r] = v.x; Al[k + 1][r] = v.y; Al[k + 2][r] = v.z; Al[k + 3][r] = v.w;
        }
        const float4* srcW = reinterpret_cast<const float4*>(W + (size_t)(n_base + r) * 128 + kq);
        #pragma unroll
        for (int i = 0; i < 8; ++i) {
            float4 v = srcW[i];
            int k = kq + 4 * i;
            Wl[k + 0][r] = v.x; Wl[k + 1][r] = v.y; Wl[k + 2][r] = v.z; Wl[k + 3][r] = v.w;
        }
    }
    __syncthreads();

    const int tm = (tid & 15) * 4;
    const int tn = (tid >> 4) * 4;
    float acc[4][4] = {};
    #pragma unroll 8
    for (int k = 0; k < 128; ++k) {
        float4 av = *reinterpret_cast<const float4*>(&Al[k][tm]);
        float4 wv = *reinterpret_cast<const float4*>(&Wl[k][tn]);
        acc[0][0] = fmaf(av.x, wv.x, acc[0][0]);
        acc[0][1] = fmaf(av.x, wv.y, acc[0][1]);
        acc[0][2] = fmaf(av.x, wv.z, acc[0][2]);
        acc[0][3] = fmaf(av.x, wv.w, acc[0][3]);
        acc[1][0] = fmaf(av.y, wv.x, acc[1][0]);
        acc[1][1] = fmaf(av.y, wv.y, acc[1][1]);
        acc[1][2] = fmaf(av.y, wv.z, acc[1][2]);
        acc[1][3] = fmaf(av.y, wv.w, acc[1][3]);
        acc[2][0] = fmaf(av.z, wv.x, acc[2][0]);
        acc[2][1] = fmaf(av.z, wv.y, acc[2][1]);
        acc[2][2] = fmaf(av.z, wv.z, acc[2][2]);
        acc[2][3] = fmaf(av.z, wv.w, acc[2][3]);
        acc[3][0] = fmaf(av.w, wv.x, acc[3][0]);
        acc[3][1] = fmaf(av.w, wv.y, acc[3][1]);
        acc[3][2] = fmaf(av.w, wv.z, acc[3][2]);
        acc[3][3] = fmaf(av.w, wv.w, acc[3][3]);
    }

    float bias[4];
    #pragma unroll
    for (int i = 0; i < 4; ++i) {
        int n = n_base + tn + i;
        bias[i] = b1[n] + (b2 ? b2[n] : 0.0f);
    }
    #pragma unroll
    for (int mi = 0; mi < 4; ++mi) {
        float4 o;
        o.x = acc[mi][0] + bias[0];
        o.y = acc[mi][1] + bias[1];
        o.z = acc[mi][2] + bias[2];
        o.w = acc[mi][3] + bias[3];
        *reinterpret_cast<float4*>(C + (size_t)(m_base + tm + mi) * N + n_base + tn) = o;
    }
}

// ---------------------------------------------------------------------------
__global__ __launch_bounds__(512)
void bn_stats_kernel(const float* __restrict__ Z,       // (T,128)
                     const float* __restrict__ gamma,
                     const float* __restrict__ beta,
                     float* __restrict__ scale,
                     float* __restrict__ shift)
{
    const int tid = threadIdx.x;
    const int col = tid & 127;
    const int seg = tid >> 7;     // 0..3
    float s = 0.f, sq = 0.f;
    for (int t = seg * 512; t < (seg + 1) * 512; ++t) {
        float v = Z[(size_t)t * 128 + col];
        s += v;
        sq = fmaf(v, v, sq);
    }
    __shared__ float ps[4][128], pq[4][128];
    ps[seg][col] = s;
    pq[seg][col] = sq;
    __syncthreads();
    if (tid < 128) {
        float sum = ps[0][tid] + ps[1][tid] + ps[2][tid] + ps[3][tid];
        float sqq = pq[0][tid] + pq[1][tid] + pq[2][tid] + pq[3][tid];
        float mean = sum * (1.0f / 2048.0f);
        float var  = sqq * (1.0f / 2048.0f) - mean * mean;
        float sc = gamma[tid] * rsqrtf(var + 1e-5f);
        scale[tid] = sc;
        shift[tid] = beta[tid] - mean * sc;
    }
}

// ---------------------------------------------------------------------------
__global__ __launch_bounds__(512)
void fc2_kernel(const float* __restrict__ Z,      // (T,128)
                const float* __restrict__ scale,
                const float* __restrict__ shift,
                const float* __restrict__ fc2_w,  // (8,128)
                const float* __restrict__ fc2_b,
                float* __restrict__ out)          // (T,8)
{
    const int gid = blockIdx.x * blockDim.x + threadIdx.x;   // 0..16383
    const int o = gid & 7;
    const int t = gid >> 3;

    __shared__ float w_s[8][132];
    __shared__ float sc_s[128], sh_s[128];
    for (int i = threadIdx.x; i < 1024; i += 512) w_s[i >> 7][i & 127] = fc2_w[i];
    if (threadIdx.x < 128) {
        sc_s[threadIdx.x] = scale[threadIdx.x];
        sh_s[threadIdx.x] = shift[threadIdx.x];
    }
    __syncthreads();

    float acc = fc2_b[o];
    const float* zrow = Z + (size_t)t * 128;
    #pragma unroll 4
    for (int k = 0; k < 128; ++k) {
        float zn = fmaf(zrow[k], sc_s[k], sh_s[k]);
        zn = fmaxf(zn, 0.0f);
        acc = fmaf(zn, w_s[o][k], acc);
    }
    out[gid] = acc;
}

// ---------------------------------------------------------------------------
extern "C" void kernel_launch(void* const* d_in, const int* in_sizes, int n_in,
                              void* d_out, int out_size, void* d_ws, size_t ws_size,
                              hipStream_t stream)
{
    const float* x     = (const float*)d_in[0];   // (2048,128,1)
    const float* Wih0  = (const float*)d_in[1];   // (512,1)
    const float* Whh0  = (const float*)d_in[2];   // (512,128)
    const float* bih0  = (const float*)d_in[3];
    const float* bhh0  = (const float*)d_in[4];
    const float* Wih1  = (const float*)d_in[5];   // (512,128)
    const float* Whh1  = (const float*)d_in[6];   // (512,128)
    const float* bih1  = (const float*)d_in[7];
    const float* bhh1  = (const float*)d_in[8];
    const float* fc1_w = (const float*)d_in[9];   // (128,128)
    const float* fc1_b = (const float*)d_in[10];
    const float* gamma = (const float*)d_in[11];
    const float* beta  = (const float*)d_in[12];
    const float* fc2_w = (const float*)d_in[13];  // (8,128)
    const float* fc2_b = (const float*)d_in[14];
    float* out = (float*)d_out;                    // (2048,8) fp32

    unsigned int* flags1 = (unsigned int*)d_ws;                   // 128 u32
    unsigned int* flags2 = flags1 + 256;                          // 128 u32
    _Float16* h1h  = (_Float16*)((char*)d_ws + 2048);             // 2048*128 f16
    float*    G    = (float*)((char*)d_ws + 2048 + T_STEPS * HID * 2);  // 2048*512
    float*    h2   = G + (size_t)T_STEPS * G4;
    float*    z    = h2 + T_STEPS * HID;
    float*    scale= z  + T_STEPS * HID;
    float*    shift= scale + 128;

    // reset chunk flags each launch (graph-capturable stream op)
    hipMemsetAsync(flags1, 0, 2048, stream);

    // K1: 3-CU pipeline (B0 = L0, B1 = G-GEMM, B2 = L1)
    lstm_pipe3<<<3, 256, 0, stream>>>(Whh0, Whh1, Wih1, x, Wih0,
                                      bih0, bhh0, bih1, bhh1,
                                      flags1, flags2, h1h, G, h2);

    // K4a: z = h2 @ fc1^T + fc1_b
    dim3 g4(T_STEPS / BM, HID / BN);
    gemm_bias_kernel<<<g4, 256, 0, stream>>>(h2, fc1_w, fc1_b, nullptr, z, T_STEPS, HID);

    // K4b: batchnorm stats over T axis
    bn_stats_kernel<<<1, 512, 0, stream>>>(z, gamma, beta, scale, shift);

    // K4c: normalize + relu + fc2
    fc2_kernel<<<T_STEPS * 8 / 512, 512, 0, stream>>>(z, scale, shift, fc2_w, fc2_b, out);
}